// Round 1
// baseline (3370.146 us; speedup 1.0000x reference)
//
#include <hip/hip_runtime.h>
#include <math.h>

#define IN_CH   256
#define HEADS   8
#define OUT_CH  32
// HEADS*OUT_CH == IN_CH == 256

// ---------------------------------------------------------------------------
// Kernel 1: xp = x @ W^T   (C[M,256] = A[M,256] * B[256,256]^T, fp32)
// 64x64 block tile, BK=16, 256 threads, 4x4 micro-tile per thread.
// ---------------------------------------------------------------------------
__global__ __launch_bounds__(256) void gemm_xwt(
    const float* __restrict__ A, const float* __restrict__ B,
    float* __restrict__ C, int M) {
  constexpr int BM = 64, BN = 64, BK = 16;
  __shared__ float As[BK][BM];
  __shared__ float Bs[BK][BN];

  const int tid  = threadIdx.x;
  const int row0 = blockIdx.x * BM;
  const int col0 = blockIdx.y * BN;
  const int tx = tid & 15;        // 0..15 (col group)
  const int ty = tid >> 4;        // 0..15 (row group)
  const int lm = tid >> 2;        // 0..63 (tile row to load)
  const int lk = (tid & 3) * 4;   // 0,4,8,12 (k quad to load)

  float acc[4][4] = {};

  for (int k0 = 0; k0 < IN_CH; k0 += BK) {
    // load A tile (guard rows) and B tile (always in range: col0+lm < 256)
    const int arow = row0 + lm;
    float4 av = make_float4(0.f, 0.f, 0.f, 0.f);
    if (arow < M) av = *(const float4*)(A + (size_t)arow * IN_CH + k0 + lk);
    As[lk + 0][lm] = av.x; As[lk + 1][lm] = av.y;
    As[lk + 2][lm] = av.z; As[lk + 3][lm] = av.w;

    float4 bv = *(const float4*)(B + (size_t)(col0 + lm) * IN_CH + k0 + lk);
    Bs[lk + 0][lm] = bv.x; Bs[lk + 1][lm] = bv.y;
    Bs[lk + 2][lm] = bv.z; Bs[lk + 3][lm] = bv.w;

    __syncthreads();

#pragma unroll
    for (int k = 0; k < BK; ++k) {
      float a[4], b[4];
#pragma unroll
      for (int i = 0; i < 4; ++i) a[i] = As[k][ty * 4 + i];
#pragma unroll
      for (int j = 0; j < 4; ++j) b[j] = Bs[k][tx * 4 + j];
#pragma unroll
      for (int i = 0; i < 4; ++i)
#pragma unroll
        for (int j = 0; j < 4; ++j) acc[i][j] = fmaf(a[i], b[j], acc[i][j]);
    }
    __syncthreads();
  }

#pragma unroll
  for (int i = 0; i < 4; ++i) {
    const int row = row0 + ty * 4 + i;
    if (row < M) {
      float4 v = make_float4(acc[i][0], acc[i][1], acc[i][2], acc[i][3]);
      *(float4*)(C + (size_t)row * IN_CH + col0 + tx * 4) = v;
    }
  }
}

// ---------------------------------------------------------------------------
// Kernel 2: al[i,h] = <xp[i,h,:], attn_l[h,:]>,  ar likewise. One thread per
// (node, head).
// ---------------------------------------------------------------------------
__global__ __launch_bounds__(256) void node_attn(
    const float* __restrict__ xp, const float* __restrict__ attn_l,
    const float* __restrict__ attn_r, float* __restrict__ al,
    float* __restrict__ ar, int n) {
  const int idx = blockIdx.x * blockDim.x + threadIdx.x;
  if (idx >= n * HEADS) return;
  const int i = idx / HEADS;
  const int h = idx % HEADS;
  const float4* xv = (const float4*)(xp + (size_t)i * IN_CH + h * OUT_CH);
  const float4* lv = (const float4*)(attn_l + h * OUT_CH);
  const float4* rv = (const float4*)(attn_r + h * OUT_CH);
  float sl = 0.f, sr = 0.f;
#pragma unroll
  for (int q = 0; q < OUT_CH / 4; ++q) {
    float4 v = xv[q], a = lv[q], b = rv[q];
    sl += v.x * a.x + v.y * a.y + v.z * a.z + v.w * a.w;
    sr += v.x * b.x + v.y * b.y + v.z * b.z + v.w * b.w;
  }
  al[idx] = sl;
  ar[idx] = sr;
}

// ---------------------------------------------------------------------------
// Kernel 3: per-edge exp(leaky_relu(logit)) accumulated into alpha_sum[dst,h].
// Global-max subtraction is skipped: it cancels exactly in the softmax and the
// 1e-6 clamp cannot trigger (every dst has a self-loop; logits are O(10)).
// One thread per edge (incl. virtual self-loops e >= E).
// ---------------------------------------------------------------------------
__global__ __launch_bounds__(256) void edge_softmax_sum(
    const int* __restrict__ src_idx, const int* __restrict__ dst_idx,
    const float* __restrict__ al, const float* __restrict__ ar,
    float* __restrict__ alpha_sum, int E, int n) {
  const int e = blockIdx.x * blockDim.x + threadIdx.x;
  const int Etot = E + n;
  if (e >= Etot) return;
  int s, d;
  if (e < E) {
    s = src_idx[e];
    d = dst_idx[e];
  } else {
    s = d = e - E;
  }
#pragma unroll
  for (int h = 0; h < HEADS; ++h) {
    float a = al[s * HEADS + h] + ar[d * HEADS + h];
    a = a > 0.f ? a : 0.2f * a;
    atomicAdd(&alpha_sum[d * HEADS + h], __expf(a));
  }
}

// ---------------------------------------------------------------------------
// Kernel 4: aggregation. One wave (64 lanes) per edge; lane l handles head
// l/8, channels (l%8)*4 .. +3, i.e. the wave covers the full 256-float
// payload with float4s. Recomputes alpha (cheaper than storing 27 MB).
// ---------------------------------------------------------------------------
__global__ __launch_bounds__(256) void edge_aggregate(
    const int* __restrict__ src_idx, const int* __restrict__ dst_idx,
    const float* __restrict__ xp, const float* __restrict__ al,
    const float* __restrict__ ar, const float* __restrict__ alpha_sum,
    float* __restrict__ out, int E, int n) {
  const int gid = blockIdx.x * blockDim.x + threadIdx.x;
  const int e = gid >> 6;   // wave id = edge id
  const int lane = gid & 63;
  const int Etot = E + n;
  if (e >= Etot) return;
  int s, d;
  if (e < E) {
    s = src_idx[e];
    d = dst_idx[e];
  } else {
    s = d = e - E;
  }
  const int h = lane >> 3;            // 0..7
  const int c = (lane & 7) * 4;       // 0,4,...,28
  float a = al[s * HEADS + h] + ar[d * HEADS + h];
  a = a > 0.f ? a : 0.2f * a;
  const float alpha =
      __expf(a) / fmaxf(alpha_sum[d * HEADS + h], 1e-6f);

  const float4 v = *(const float4*)(xp + (size_t)s * IN_CH + lane * 4);
  float* o = out + (size_t)d * IN_CH + h * OUT_CH + c;
  atomicAdd(o + 0, alpha * v.x);
  atomicAdd(o + 1, alpha * v.y);
  atomicAdd(o + 2, alpha * v.z);
  atomicAdd(o + 3, alpha * v.w);
}

// ---------------------------------------------------------------------------
extern "C" void kernel_launch(void* const* d_in, const int* in_sizes, int n_in,
                              void* d_out, int out_size, void* d_ws,
                              size_t ws_size, hipStream_t stream) {
  const float* x      = (const float*)d_in[0];
  const int*   ei     = (const int*)d_in[1];   // [2, E] flat: row0=src, row1=dst
  const float* W      = (const float*)d_in[2];
  const float* attn_l = (const float*)d_in[3];
  const float* attn_r = (const float*)d_in[4];
  float* out = (float*)d_out;

  const int n = in_sizes[0] / IN_CH;   // 50000
  const int E = in_sizes[1] / 2;       // 800000
  const int Etot = E + n;

  float* xp   = (float*)d_ws;                  // n * 256
  float* al   = xp + (size_t)n * IN_CH;        // n * 8
  float* ar   = al + (size_t)n * HEADS;        // n * 8
  float* asum = ar + (size_t)n * HEADS;        // n * 8

  hipMemsetAsync(asum, 0, (size_t)n * HEADS * sizeof(float), stream);
  hipMemsetAsync(out, 0, (size_t)out_size * sizeof(float), stream);

  dim3 gemm_grid((n + 63) / 64, IN_CH / 64);
  gemm_xwt<<<gemm_grid, 256, 0, stream>>>(x, W, xp, n);

  node_attn<<<(n * HEADS + 255) / 256, 256, 0, stream>>>(xp, attn_l, attn_r,
                                                         al, ar, n);

  edge_softmax_sum<<<(Etot + 255) / 256, 256, 0, stream>>>(ei, ei + E, al, ar,
                                                           asum, E, n);

  const long long agg_threads = (long long)Etot * 64;
  edge_aggregate<<<(int)((agg_threads + 255) / 256), 256, 0, stream>>>(
      ei, ei + E, xp, al, ar, asum, out, E, n);
}

// Round 2
// 503.329 us; speedup vs baseline: 6.6957x; 6.6957x over previous
//
#include <hip/hip_runtime.h>
#include <math.h>

#define IN_CH   256
#define HEADS   8
#define OUT_CH  32
// HEADS*OUT_CH == IN_CH == 256

// ---------------------------------------------------------------------------
// Kernel 1: xp = x @ W^T   (C[M,256] = A[M,256] * B[256,256]^T, fp32)
// 64x64 block tile, BK=16, 256 threads, 4x4 micro-tile per thread.
// ---------------------------------------------------------------------------
__global__ __launch_bounds__(256) void gemm_xwt(
    const float* __restrict__ A, const float* __restrict__ B,
    float* __restrict__ C, int M) {
  constexpr int BM = 64, BN = 64, BK = 16;
  __shared__ float As[BK][BM];
  __shared__ float Bs[BK][BN];

  const int tid  = threadIdx.x;
  const int row0 = blockIdx.x * BM;
  const int col0 = blockIdx.y * BN;
  const int tx = tid & 15;        // 0..15 (col group)
  const int ty = tid >> 4;        // 0..15 (row group)
  const int lm = tid >> 2;        // 0..63 (tile row to load)
  const int lk = (tid & 3) * 4;   // 0,4,8,12 (k quad to load)

  float acc[4][4] = {};

  for (int k0 = 0; k0 < IN_CH; k0 += BK) {
    const int arow = row0 + lm;
    float4 av = make_float4(0.f, 0.f, 0.f, 0.f);
    if (arow < M) av = *(const float4*)(A + (size_t)arow * IN_CH + k0 + lk);
    As[lk + 0][lm] = av.x; As[lk + 1][lm] = av.y;
    As[lk + 2][lm] = av.z; As[lk + 3][lm] = av.w;

    float4 bv = *(const float4*)(B + (size_t)(col0 + lm) * IN_CH + k0 + lk);
    Bs[lk + 0][lm] = bv.x; Bs[lk + 1][lm] = bv.y;
    Bs[lk + 2][lm] = bv.z; Bs[lk + 3][lm] = bv.w;

    __syncthreads();

#pragma unroll
    for (int k = 0; k < BK; ++k) {
      float a[4], b[4];
#pragma unroll
      for (int i = 0; i < 4; ++i) a[i] = As[k][ty * 4 + i];
#pragma unroll
      for (int j = 0; j < 4; ++j) b[j] = Bs[k][tx * 4 + j];
#pragma unroll
      for (int i = 0; i < 4; ++i)
#pragma unroll
        for (int j = 0; j < 4; ++j) acc[i][j] = fmaf(a[i], b[j], acc[i][j]);
    }
    __syncthreads();
  }

#pragma unroll
  for (int i = 0; i < 4; ++i) {
    const int row = row0 + ty * 4 + i;
    if (row < M) {
      float4 v = make_float4(acc[i][0], acc[i][1], acc[i][2], acc[i][3]);
      *(float4*)(C + (size_t)row * IN_CH + col0 + tx * 4) = v;
    }
  }
}

// ---------------------------------------------------------------------------
// Kernel 2: al[i,h] = <xp[i,h,:], attn_l[h,:]>, ar likewise.
// ---------------------------------------------------------------------------
__global__ __launch_bounds__(256) void node_attn(
    const float* __restrict__ xp, const float* __restrict__ attn_l,
    const float* __restrict__ attn_r, float* __restrict__ al,
    float* __restrict__ ar, int n) {
  const int idx = blockIdx.x * blockDim.x + threadIdx.x;
  if (idx >= n * HEADS) return;
  const int i = idx / HEADS;
  const int h = idx % HEADS;
  const float4* xv = (const float4*)(xp + (size_t)i * IN_CH + h * OUT_CH);
  const float4* lv = (const float4*)(attn_l + h * OUT_CH);
  const float4* rv = (const float4*)(attn_r + h * OUT_CH);
  float sl = 0.f, sr = 0.f;
#pragma unroll
  for (int q = 0; q < OUT_CH / 4; ++q) {
    float4 v = xv[q], a = lv[q], b = rv[q];
    sl += v.x * a.x + v.y * a.y + v.z * a.z + v.w * a.w;
    sr += v.x * b.x + v.y * b.y + v.z * b.z + v.w * b.w;
  }
  al[idx] = sl;
  ar[idx] = sr;
}

// ---------------------------------------------------------------------------
// Kernel 3a: in-degree histogram over dst (self-loops included: e >= E -> e-E).
// ---------------------------------------------------------------------------
__global__ __launch_bounds__(256) void csr_count(
    const int* __restrict__ dst_idx, int* __restrict__ deg, int E, int n) {
  const int e = blockIdx.x * blockDim.x + threadIdx.x;
  const int Etot = E + n;
  if (e >= Etot) return;
  const int d = (e < E) ? dst_idx[e] : (e - E);
  atomicAdd(&deg[d], 1);
}

// ---------------------------------------------------------------------------
// Kernel 3b: exclusive scan of deg -> off. Single block, 256 threads, chunked.
// n = 50000 -> ~196 elems/thread. Serial scan of 256 partials by thread 0.
// ---------------------------------------------------------------------------
__global__ __launch_bounds__(256) void csr_scan(
    const int* __restrict__ deg, int* __restrict__ off, int n) {
  __shared__ int partial[256];
  const int chunk = (n + 255) / 256;
  const int lo = threadIdx.x * chunk;
  const int hi = min(lo + chunk, n);
  int s = 0;
  for (int i = lo; i < hi; ++i) s += deg[i];
  partial[threadIdx.x] = s;
  __syncthreads();
  if (threadIdx.x == 0) {
    int run = 0;
    for (int t = 0; t < 256; ++t) {
      int v = partial[t];
      partial[t] = run;
      run += v;
    }
  }
  __syncthreads();
  int run = partial[threadIdx.x];
  for (int i = lo; i < hi; ++i) {
    off[i] = run;
    run += deg[i];
  }
}

// ---------------------------------------------------------------------------
// Kernel 3c: bucket fill: csr_src[off[d] + pos] = s.
// ---------------------------------------------------------------------------
__global__ __launch_bounds__(256) void csr_fill(
    const int* __restrict__ src_idx, const int* __restrict__ dst_idx,
    const int* __restrict__ off, int* __restrict__ cnt,
    int* __restrict__ csr_src, int E, int n) {
  const int e = blockIdx.x * blockDim.x + threadIdx.x;
  const int Etot = E + n;
  if (e >= Etot) return;
  int s, d;
  if (e < E) {
    s = src_idx[e];
    d = dst_idx[e];
  } else {
    s = d = e - E;
  }
  const int p = atomicAdd(&cnt[d], 1);
  csr_src[off[d] + p] = s;
}

// ---------------------------------------------------------------------------
// Kernel 4: gather-aggregate. One wave per dst node. Lane l covers head
// l>>3, channels (l&7)*4..+3 (lane*4 spans the full 256-wide row). In one
// pass over the dst's in-edges, accumulate softmax denominator (per head)
// and weighted numerator (per lane float4); divide at the end; single
// coalesced 1 KB store per node. No atomics.
// Softmax max-subtraction cancels exactly; 1e-6 clamp can't trigger (the
// self-loop term alone is >= exp(-0.2*|a|) >> 1e-6).
// ---------------------------------------------------------------------------
__global__ __launch_bounds__(256) void gat_gather(
    const int* __restrict__ csr_src, const int* __restrict__ off,
    const int* __restrict__ deg, const float* __restrict__ xp,
    const float* __restrict__ al, const float* __restrict__ ar,
    float* __restrict__ out, int n) {
  const int gid = blockIdx.x * blockDim.x + threadIdx.x;
  const int d = gid >> 6;
  const int lane = gid & 63;
  if (d >= n) return;
  const int h = lane >> 3;
  const int start = off[d];
  const int cnt = deg[d];
  const float ard = ar[d * HEADS + h];

  float4 acc = make_float4(0.f, 0.f, 0.f, 0.f);
  float denom = 0.f;
  for (int j = 0; j < cnt; ++j) {
    const int s = csr_src[start + j];
    float a = al[s * HEADS + h] + ard;
    a = a > 0.f ? a : 0.2f * a;
    const float w = __expf(a);
    denom += w;
    const float4 v = *(const float4*)(xp + (size_t)s * IN_CH + lane * 4);
    acc.x = fmaf(w, v.x, acc.x);
    acc.y = fmaf(w, v.y, acc.y);
    acc.z = fmaf(w, v.z, acc.z);
    acc.w = fmaf(w, v.w, acc.w);
  }
  const float inv = 1.f / fmaxf(denom, 1e-6f);
  acc.x *= inv; acc.y *= inv; acc.z *= inv; acc.w *= inv;
  *(float4*)(out + (size_t)d * IN_CH + lane * 4) = acc;
}

// ---------------------------------------------------------------------------
extern "C" void kernel_launch(void* const* d_in, const int* in_sizes, int n_in,
                              void* d_out, int out_size, void* d_ws,
                              size_t ws_size, hipStream_t stream) {
  const float* x      = (const float*)d_in[0];
  const int*   ei     = (const int*)d_in[1];   // [2, E]: row0=src, row1=dst
  const float* W      = (const float*)d_in[2];
  const float* attn_l = (const float*)d_in[3];
  const float* attn_r = (const float*)d_in[4];
  float* out = (float*)d_out;

  const int n = in_sizes[0] / IN_CH;   // 50000
  const int E = in_sizes[1] / 2;       // 800000
  const int Etot = E + n;

  float* xp   = (float*)d_ws;                    // n*256 f
  float* al   = xp + (size_t)n * IN_CH;          // n*8 f
  float* ar   = al + (size_t)n * HEADS;          // n*8 f
  int*   deg  = (int*)(ar + (size_t)n * HEADS);  // n i  (zeroed)
  int*   cnt  = deg + n;                         // n i  (zeroed)
  int*   off  = cnt + n;                         // n i
  int*   csrs = off + n;                         // Etot i

  // zero deg + cnt in one shot (adjacent)
  hipMemsetAsync(deg, 0, (size_t)2 * n * sizeof(int), stream);

  dim3 gemm_grid((n + 63) / 64, IN_CH / 64);
  gemm_xwt<<<gemm_grid, 256, 0, stream>>>(x, W, xp, n);

  node_attn<<<(n * HEADS + 255) / 256, 256, 0, stream>>>(xp, attn_l, attn_r,
                                                         al, ar, n);

  csr_count<<<(Etot + 255) / 256, 256, 0, stream>>>(ei + E, deg, E, n);
  csr_scan<<<1, 256, 0, stream>>>(deg, off, n);
  csr_fill<<<(Etot + 255) / 256, 256, 0, stream>>>(ei, ei + E, off, cnt, csrs,
                                                   E, n);

  const long long g_threads = (long long)n * 64;
  gat_gather<<<(int)((g_threads + 255) / 256), 256, 0, stream>>>(
      csrs, off, deg, xp, al, ar, out, n);
}

// Round 3
// 387.215 us; speedup vs baseline: 8.7035x; 1.2999x over previous
//
#include <hip/hip_runtime.h>
#include <math.h>

#define IN_CH   256
#define HEADS   8
#define OUT_CH  32
// HEADS*OUT_CH == IN_CH == 256

typedef __attribute__((ext_vector_type(8))) short s16x8;   // 8 bf16 (4 VGPRs)
typedef __attribute__((ext_vector_type(4))) float f32x4;   // MFMA C/D

__device__ inline short f2bf(float f) {
  unsigned u = __builtin_bit_cast(unsigned, f);
  u += 0x7fffu + ((u >> 16) & 1u);           // RNE
  return (short)(u >> 16);
}
__device__ inline float bf2f(unsigned short u) {
  unsigned v = ((unsigned)u) << 16;
  return __builtin_bit_cast(float, v);
}

// ---------------------------------------------------------------------------
// Kernel 0: W fp32 -> bf16 (one-shot, 65536 elements).
// ---------------------------------------------------------------------------
__global__ __launch_bounds__(256) void w_convert(const float* __restrict__ W,
                                                 short* __restrict__ Wb) {
  const int i = blockIdx.x * blockDim.x + threadIdx.x;
  if (i < IN_CH * IN_CH) Wb[i] = f2bf(W[i]);
}

// ---------------------------------------------------------------------------
// Kernel 1: xp_bf16 = bf16(x @ W^T) via MFMA 16x16x32.
// One wave per block, M-tile = 32 (2 subtiles of 16). A-frags for all K=256
// held in registers (64 VGPRs); loop over 16 N-tiles streaming B-frags from
// W_bf16 (L2-resident, 128 KB). No LDS, no barriers.
// A: lane holds x[m0+ms*16+(lane&15)][32*ks + (lane>>4)*8 + j]
// B: lane holds W[t*16+(lane&15)][32*ks + (lane>>4)*8 + j]
// D: col = lane&15 (n), row = (lane>>4)*4 + reg (m)
// ---------------------------------------------------------------------------
__global__ __launch_bounds__(64) void gemm_mfma(const float* __restrict__ x,
                                                const short* __restrict__ Wb,
                                                short* __restrict__ xpb,
                                                int M) {
  const int lane = threadIdx.x;
  const int m0 = blockIdx.x * 32;
  const int mrow = lane & 15;
  const int kq = lane >> 4;

  s16x8 afrag[2][8];
#pragma unroll
  for (int ms = 0; ms < 2; ++ms) {
    int m = m0 + ms * 16 + mrow;
    if (m >= M) m = M - 1;   // clamp; stores are guarded
    const float* xr = x + (size_t)m * IN_CH + kq * 8;
#pragma unroll
    for (int ks = 0; ks < 8; ++ks) {
      float4 lo = *(const float4*)(xr + ks * 32);
      float4 hi = *(const float4*)(xr + ks * 32 + 4);
      s16x8 a;
      a[0] = f2bf(lo.x); a[1] = f2bf(lo.y); a[2] = f2bf(lo.z); a[3] = f2bf(lo.w);
      a[4] = f2bf(hi.x); a[5] = f2bf(hi.y); a[6] = f2bf(hi.z); a[7] = f2bf(hi.w);
      afrag[ms][ks] = a;
    }
  }

#pragma unroll 2
  for (int t = 0; t < 16; ++t) {
    f32x4 acc0 = {0.f, 0.f, 0.f, 0.f};
    f32x4 acc1 = {0.f, 0.f, 0.f, 0.f};
    const short* wr = Wb + (size_t)(t * 16 + mrow) * IN_CH + kq * 8;
#pragma unroll
    for (int ks = 0; ks < 8; ++ks) {
      s16x8 b = *(const s16x8*)(wr + ks * 32);
      acc0 = __builtin_amdgcn_mfma_f32_16x16x32_bf16(afrag[0][ks], b, acc0, 0, 0, 0);
      acc1 = __builtin_amdgcn_mfma_f32_16x16x32_bf16(afrag[1][ks], b, acc1, 0, 0, 0);
    }
    const int col = t * 16 + mrow;
#pragma unroll
    for (int r = 0; r < 4; ++r) {
      const int row0r = m0 + kq * 4 + r;
      if (row0r < M) xpb[(size_t)row0r * IN_CH + col] = f2bf(acc0[r]);
      const int row1r = m0 + 16 + kq * 4 + r;
      if (row1r < M) xpb[(size_t)row1r * IN_CH + col] = f2bf(acc1[r]);
    }
  }
}

// ---------------------------------------------------------------------------
// Kernel 2: al/ar from bf16 xp. One thread per (node, head).
// ---------------------------------------------------------------------------
__global__ __launch_bounds__(256) void node_attn(
    const short* __restrict__ xpb, const float* __restrict__ attn_l,
    const float* __restrict__ attn_r, float* __restrict__ al,
    float* __restrict__ ar, int n) {
  const int idx = blockIdx.x * blockDim.x + threadIdx.x;
  if (idx >= n * HEADS) return;
  const int i = idx >> 3;
  const int h = idx & 7;
  const ushort4* xv = (const ushort4*)(xpb + (size_t)i * IN_CH + h * OUT_CH);
  const float* lp = attn_l + h * OUT_CH;
  const float* rp = attn_r + h * OUT_CH;
  float sl = 0.f, sr = 0.f;
#pragma unroll
  for (int q = 0; q < 8; ++q) {
    ushort4 u = xv[q];
    float v0 = bf2f(u.x), v1 = bf2f(u.y), v2 = bf2f(u.z), v3 = bf2f(u.w);
    sl += v0 * lp[q * 4] + v1 * lp[q * 4 + 1] + v2 * lp[q * 4 + 2] + v3 * lp[q * 4 + 3];
    sr += v0 * rp[q * 4] + v1 * rp[q * 4 + 1] + v2 * rp[q * 4 + 2] + v3 * rp[q * 4 + 3];
  }
  al[idx] = sl;
  ar[idx] = sr;
}

// ---------------------------------------------------------------------------
// Kernel 3a: in-degree histogram over dst (self-loops: e >= E -> e-E).
// ---------------------------------------------------------------------------
__global__ __launch_bounds__(256) void csr_count(
    const int* __restrict__ dst_idx, int* __restrict__ deg, int E, int n) {
  const int e = blockIdx.x * blockDim.x + threadIdx.x;
  if (e >= E + n) return;
  const int d = (e < E) ? dst_idx[e] : (e - E);
  atomicAdd(&deg[d], 1);
}

// ---------------------------------------------------------------------------
// Kernel 3b: exclusive scan deg -> off. Single block, 256 threads.
// ---------------------------------------------------------------------------
__global__ __launch_bounds__(256) void csr_scan(
    const int* __restrict__ deg, int* __restrict__ off, int n) {
  __shared__ int partial[256];
  const int chunk = (n + 255) / 256;
  const int lo = threadIdx.x * chunk;
  const int hi = min(lo + chunk, n);
  int s = 0;
  for (int i = lo; i < hi; ++i) s += deg[i];
  partial[threadIdx.x] = s;
  __syncthreads();
  if (threadIdx.x == 0) {
    int run = 0;
    for (int t = 0; t < 256; ++t) {
      int v = partial[t];
      partial[t] = run;
      run += v;
    }
  }
  __syncthreads();
  int run = partial[threadIdx.x];
  for (int i = lo; i < hi; ++i) {
    off[i] = run;
    run += deg[i];
  }
}

// ---------------------------------------------------------------------------
// Kernel 3c: bucket fill: csr_src[off[d] + pos] = s.
// ---------------------------------------------------------------------------
__global__ __launch_bounds__(256) void csr_fill(
    const int* __restrict__ src_idx, const int* __restrict__ dst_idx,
    const int* __restrict__ off, int* __restrict__ cnt,
    int* __restrict__ csr_src, int E, int n) {
  const int e = blockIdx.x * blockDim.x + threadIdx.x;
  if (e >= E + n) return;
  int s, d;
  if (e < E) {
    s = src_idx[e];
    d = dst_idx[e];
  } else {
    s = d = e - E;
  }
  const int p = atomicAdd(&cnt[d], 1);
  csr_src[off[d] + p] = s;
}

// ---------------------------------------------------------------------------
// Kernel 4: gather-aggregate, bf16 payload. One wave per dst node; lane l
// covers channels l*4..l*4+3 (head = l>>3). Accumulates softmax denominator
// and weighted numerator in one pass; fp32 accumulate; single coalesced
// 1 KB fp32 store per node. 2-edge manual unroll for MLP.
// Softmax max-subtraction cancels exactly; 1e-6 clamp can't trigger
// (self-loop term >= exp(-|a|·0.2) >> 1e-6).
// ---------------------------------------------------------------------------
__global__ __launch_bounds__(256) void gat_gather(
    const int* __restrict__ csr_src, const int* __restrict__ off,
    const int* __restrict__ deg, const short* __restrict__ xpb,
    const float* __restrict__ al, const float* __restrict__ ar,
    float* __restrict__ out, int n) {
  const int gid = blockIdx.x * blockDim.x + threadIdx.x;
  const int d = gid >> 6;
  const int lane = gid & 63;
  if (d >= n) return;
  const int h = lane >> 3;
  const int start = off[d];
  const int cnt = deg[d];
  const float ard = ar[d * HEADS + h];

  float4 acc = make_float4(0.f, 0.f, 0.f, 0.f);
  float denom = 0.f;
  int j = 0;
  for (; j + 2 <= cnt; j += 2) {
    const int s0 = csr_src[start + j];
    const int s1 = csr_src[start + j + 1];
    const ushort4 u0 = *(const ushort4*)(xpb + (size_t)s0 * IN_CH + lane * 4);
    const ushort4 u1 = *(const ushort4*)(xpb + (size_t)s1 * IN_CH + lane * 4);
    float a0 = al[s0 * HEADS + h] + ard;
    float a1 = al[s1 * HEADS + h] + ard;
    a0 = a0 > 0.f ? a0 : 0.2f * a0;
    a1 = a1 > 0.f ? a1 : 0.2f * a1;
    const float w0 = __expf(a0);
    const float w1 = __expf(a1);
    denom += w0 + w1;
    acc.x = fmaf(w0, bf2f(u0.x), acc.x);
    acc.y = fmaf(w0, bf2f(u0.y), acc.y);
    acc.z = fmaf(w0, bf2f(u0.z), acc.z);
    acc.w = fmaf(w0, bf2f(u0.w), acc.w);
    acc.x = fmaf(w1, bf2f(u1.x), acc.x);
    acc.y = fmaf(w1, bf2f(u1.y), acc.y);
    acc.z = fmaf(w1, bf2f(u1.z), acc.z);
    acc.w = fmaf(w1, bf2f(u1.w), acc.w);
  }
  if (j < cnt) {
    const int s0 = csr_src[start + j];
    const ushort4 u0 = *(const ushort4*)(xpb + (size_t)s0 * IN_CH + lane * 4);
    float a0 = al[s0 * HEADS + h] + ard;
    a0 = a0 > 0.f ? a0 : 0.2f * a0;
    const float w0 = __expf(a0);
    denom += w0;
    acc.x = fmaf(w0, bf2f(u0.x), acc.x);
    acc.y = fmaf(w0, bf2f(u0.y), acc.y);
    acc.z = fmaf(w0, bf2f(u0.z), acc.z);
    acc.w = fmaf(w0, bf2f(u0.w), acc.w);
  }
  const float inv = 1.f / fmaxf(denom, 1e-6f);
  acc.x *= inv; acc.y *= inv; acc.z *= inv; acc.w *= inv;
  *(float4*)(out + (size_t)d * IN_CH + lane * 4) = acc;
}

// ---------------------------------------------------------------------------
extern "C" void kernel_launch(void* const* d_in, const int* in_sizes, int n_in,
                              void* d_out, int out_size, void* d_ws,
                              size_t ws_size, hipStream_t stream) {
  const float* x      = (const float*)d_in[0];
  const int*   ei     = (const int*)d_in[1];   // [2, E]: row0=src, row1=dst
  const float* W      = (const float*)d_in[2];
  const float* attn_l = (const float*)d_in[3];
  const float* attn_r = (const float*)d_in[4];
  float* out = (float*)d_out;

  const int n = in_sizes[0] / IN_CH;   // 50000
  const int E = in_sizes[1] / 2;       // 800000
  const int Etot = E + n;

  short* xpb = (short*)d_ws;                       // n*256 bf16
  short* Wb  = xpb + (size_t)n * IN_CH;            // 65536 bf16
  float* al  = (float*)(Wb + IN_CH * IN_CH);       // n*8 f
  float* ar  = al + (size_t)n * HEADS;             // n*8 f
  int*   deg = (int*)(ar + (size_t)n * HEADS);     // n i (zeroed)
  int*   cnt = deg + n;                            // n i (zeroed)
  int*   off = cnt + n;                            // n i
  int*   csrs = off + n;                           // Etot i

  hipMemsetAsync(deg, 0, (size_t)2 * n * sizeof(int), stream);

  w_convert<<<(IN_CH * IN_CH + 255) / 256, 256, 0, stream>>>(W, Wb);

  gemm_mfma<<<(n + 31) / 32, 64, 0, stream>>>(x, Wb, xpb, n);

  node_attn<<<(n * HEADS + 255) / 256, 256, 0, stream>>>(xpb, attn_l, attn_r,
                                                         al, ar, n);

  csr_count<<<(Etot + 255) / 256, 256, 0, stream>>>(ei + E, deg, E, n);
  csr_scan<<<1, 256, 0, stream>>>(deg, off, n);
  csr_fill<<<(Etot + 255) / 256, 256, 0, stream>>>(ei, ei + E, off, cnt, csrs,
                                                   E, n);

  const long long g_threads = (long long)n * 64;
  gat_gather<<<(int)((g_threads + 255) / 256), 256, 0, stream>>>(
      csrs, off, deg, xpb, al, ar, out, n);
}

// Round 4
// 314.851 us; speedup vs baseline: 10.7039x; 1.2298x over previous
//
#include <hip/hip_runtime.h>
#include <math.h>

#define IN_CH   256
#define HEADS   8
#define OUT_CH  32
// HEADS*OUT_CH == IN_CH == 256

typedef __attribute__((ext_vector_type(8))) short s16x8;   // 8 bf16 (4 VGPRs)
typedef __attribute__((ext_vector_type(4))) float f32x4;   // MFMA C/D

__device__ inline short f2bf(float f) {
  unsigned u = __builtin_bit_cast(unsigned, f);
  u += 0x7fffu + ((u >> 16) & 1u);           // RNE
  return (short)(u >> 16);
}
__device__ inline float bf2f(unsigned short u) {
  unsigned v = ((unsigned)u) << 16;
  return __builtin_bit_cast(float, v);
}

// ---------------------------------------------------------------------------
// Kernel 0: W fp32 -> bf16 (one-shot, 65536 elements).
// ---------------------------------------------------------------------------
__global__ __launch_bounds__(256) void w_convert(const float* __restrict__ W,
                                                 short* __restrict__ Wb) {
  const int i = blockIdx.x * blockDim.x + threadIdx.x;
  if (i < IN_CH * IN_CH) Wb[i] = f2bf(W[i]);
}

// ---------------------------------------------------------------------------
// Kernel 1: xp_bf16 = bf16(x @ W^T) via MFMA 16x16x32.
// One wave per block, M-tile = 32 (2 subtiles of 16). A-frags for all K=256
// held in registers; loop over 16 N-tiles streaming B-frags from W_bf16
// (L2-resident, 128 KB). No LDS, no barriers.
// ---------------------------------------------------------------------------
__global__ __launch_bounds__(64) void gemm_mfma(const float* __restrict__ x,
                                                const short* __restrict__ Wb,
                                                short* __restrict__ xpb,
                                                int M) {
  const int lane = threadIdx.x;
  const int m0 = blockIdx.x * 32;
  const int mrow = lane & 15;
  const int kq = lane >> 4;

  s16x8 afrag[2][8];
#pragma unroll
  for (int ms = 0; ms < 2; ++ms) {
    int m = m0 + ms * 16 + mrow;
    if (m >= M) m = M - 1;   // clamp; stores are guarded
    const float* xr = x + (size_t)m * IN_CH + kq * 8;
#pragma unroll
    for (int ks = 0; ks < 8; ++ks) {
      float4 lo = *(const float4*)(xr + ks * 32);
      float4 hi = *(const float4*)(xr + ks * 32 + 4);
      s16x8 a;
      a[0] = f2bf(lo.x); a[1] = f2bf(lo.y); a[2] = f2bf(lo.z); a[3] = f2bf(lo.w);
      a[4] = f2bf(hi.x); a[5] = f2bf(hi.y); a[6] = f2bf(hi.z); a[7] = f2bf(hi.w);
      afrag[ms][ks] = a;
    }
  }

#pragma unroll 2
  for (int t = 0; t < 16; ++t) {
    f32x4 acc0 = {0.f, 0.f, 0.f, 0.f};
    f32x4 acc1 = {0.f, 0.f, 0.f, 0.f};
    const short* wr = Wb + (size_t)(t * 16 + mrow) * IN_CH + kq * 8;
#pragma unroll
    for (int ks = 0; ks < 8; ++ks) {
      s16x8 b = *(const s16x8*)(wr + ks * 32);
      acc0 = __builtin_amdgcn_mfma_f32_16x16x32_bf16(afrag[0][ks], b, acc0, 0, 0, 0);
      acc1 = __builtin_amdgcn_mfma_f32_16x16x32_bf16(afrag[1][ks], b, acc1, 0, 0, 0);
    }
    const int col = t * 16 + mrow;
#pragma unroll
    for (int r = 0; r < 4; ++r) {
      const int row0r = m0 + kq * 4 + r;
      if (row0r < M) xpb[(size_t)row0r * IN_CH + col] = f2bf(acc0[r]);
      const int row1r = m0 + 16 + kq * 4 + r;
      if (row1r < M) xpb[(size_t)row1r * IN_CH + col] = f2bf(acc1[r]);
    }
  }
}

// ---------------------------------------------------------------------------
// Kernel 2: al/ar from bf16 xp. One thread per (node, head).
// ---------------------------------------------------------------------------
__global__ __launch_bounds__(256) void node_attn(
    const short* __restrict__ xpb, const float* __restrict__ attn_l,
    const float* __restrict__ attn_r, float* __restrict__ al,
    float* __restrict__ ar, int n) {
  const int idx = blockIdx.x * blockDim.x + threadIdx.x;
  if (idx >= n * HEADS) return;
  const int i = idx >> 3;
  const int h = idx & 7;
  const ushort4* xv = (const ushort4*)(xpb + (size_t)i * IN_CH + h * OUT_CH);
  const float* lp = attn_l + h * OUT_CH;
  const float* rp = attn_r + h * OUT_CH;
  float sl = 0.f, sr = 0.f;
#pragma unroll
  for (int q = 0; q < 8; ++q) {
    ushort4 u = xv[q];
    float v0 = bf2f(u.x), v1 = bf2f(u.y), v2 = bf2f(u.z), v3 = bf2f(u.w);
    sl += v0 * lp[q * 4] + v1 * lp[q * 4 + 1] + v2 * lp[q * 4 + 2] + v3 * lp[q * 4 + 3];
    sr += v0 * rp[q * 4] + v1 * rp[q * 4 + 1] + v2 * rp[q * 4 + 2] + v3 * rp[q * 4 + 3];
  }
  al[idx] = sl;
  ar[idx] = sr;
}

// ---------------------------------------------------------------------------
// Kernel 3a: in-degree histogram over dst (self-loops: e >= E -> e-E).
// ---------------------------------------------------------------------------
__global__ __launch_bounds__(256) void csr_count(
    const int* __restrict__ dst_idx, int* __restrict__ deg, int E, int n) {
  const int e = blockIdx.x * blockDim.x + threadIdx.x;
  if (e >= E + n) return;
  const int d = (e < E) ? dst_idx[e] : (e - E);
  atomicAdd(&deg[d], 1);
}

// ---------------------------------------------------------------------------
// Kernel 3b: bucket allocation WITHOUT a global scan. Buckets need not be
// ordered by d — the gather only needs a contiguous region per dst. Wave
// shuffle-scan of deg, one atomicAdd on a global cursor per wave (~780
// atomics total), off[d] = base + exclusive_prefix. Replaces the 89 us
// single-block serial scan with a fully parallel ~5 us kernel.
// ---------------------------------------------------------------------------
__global__ __launch_bounds__(256) void csr_alloc(
    const int* __restrict__ deg, int* __restrict__ off,
    int* __restrict__ cursor, int n) {
  const int d = blockIdx.x * blockDim.x + threadIdx.x;
  const int lane = threadIdx.x & 63;
  const int v = (d < n) ? deg[d] : 0;
  // inclusive scan across the wave
  int incl = v;
#pragma unroll
  for (int o = 1; o < 64; o <<= 1) {
    int t = __shfl_up(incl, o);
    if (lane >= o) incl += t;
  }
  const int total = __shfl(incl, 63);
  int base = 0;
  if (lane == 63) base = atomicAdd(cursor, total);
  base = __shfl(base, 63);
  if (d < n) off[d] = base + incl - v;
}

// ---------------------------------------------------------------------------
// Kernel 3c: bucket fill: csr_src[off[d] + pos] = s.
// ---------------------------------------------------------------------------
__global__ __launch_bounds__(256) void csr_fill(
    const int* __restrict__ src_idx, const int* __restrict__ dst_idx,
    const int* __restrict__ off, int* __restrict__ cnt,
    int* __restrict__ csr_src, int E, int n) {
  const int e = blockIdx.x * blockDim.x + threadIdx.x;
  if (e >= E + n) return;
  int s, d;
  if (e < E) {
    s = src_idx[e];
    d = dst_idx[e];
  } else {
    s = d = e - E;
  }
  const int p = atomicAdd(&cnt[d], 1);
  csr_src[off[d] + p] = s;
}

// ---------------------------------------------------------------------------
// Kernel 4: gather-aggregate, bf16 payload. One wave per dst node; lane l
// covers channels l*4..l*4+3 (head = l>>3). Softmax denominator + weighted
// numerator in one pass, fp32 accumulate, single coalesced store. No atomics.
// Max-subtraction cancels exactly; 1e-6 clamp can't trigger (self-loop).
// ---------------------------------------------------------------------------
__global__ __launch_bounds__(256) void gat_gather(
    const int* __restrict__ csr_src, const int* __restrict__ off,
    const int* __restrict__ deg, const short* __restrict__ xpb,
    const float* __restrict__ al, const float* __restrict__ ar,
    float* __restrict__ out, int n) {
  const int gid = blockIdx.x * blockDim.x + threadIdx.x;
  const int d = gid >> 6;
  const int lane = gid & 63;
  if (d >= n) return;
  const int h = lane >> 3;
  const int start = off[d];
  const int cnt = deg[d];
  const float ard = ar[d * HEADS + h];

  float4 acc = make_float4(0.f, 0.f, 0.f, 0.f);
  float denom = 0.f;
  int j = 0;
  for (; j + 2 <= cnt; j += 2) {
    const int s0 = csr_src[start + j];
    const int s1 = csr_src[start + j + 1];
    const ushort4 u0 = *(const ushort4*)(xpb + (size_t)s0 * IN_CH + lane * 4);
    const ushort4 u1 = *(const ushort4*)(xpb + (size_t)s1 * IN_CH + lane * 4);
    float a0 = al[s0 * HEADS + h] + ard;
    float a1 = al[s1 * HEADS + h] + ard;
    a0 = a0 > 0.f ? a0 : 0.2f * a0;
    a1 = a1 > 0.f ? a1 : 0.2f * a1;
    const float w0 = __expf(a0);
    const float w1 = __expf(a1);
    denom += w0 + w1;
    acc.x = fmaf(w0, bf2f(u0.x), acc.x);
    acc.y = fmaf(w0, bf2f(u0.y), acc.y);
    acc.z = fmaf(w0, bf2f(u0.z), acc.z);
    acc.w = fmaf(w0, bf2f(u0.w), acc.w);
    acc.x = fmaf(w1, bf2f(u1.x), acc.x);
    acc.y = fmaf(w1, bf2f(u1.y), acc.y);
    acc.z = fmaf(w1, bf2f(u1.z), acc.z);
    acc.w = fmaf(w1, bf2f(u1.w), acc.w);
  }
  if (j < cnt) {
    const int s0 = csr_src[start + j];
    const ushort4 u0 = *(const ushort4*)(xpb + (size_t)s0 * IN_CH + lane * 4);
    float a0 = al[s0 * HEADS + h] + ard;
    a0 = a0 > 0.f ? a0 : 0.2f * a0;
    const float w0 = __expf(a0);
    denom += w0;
    acc.x = fmaf(w0, bf2f(u0.x), acc.x);
    acc.y = fmaf(w0, bf2f(u0.y), acc.y);
    acc.z = fmaf(w0, bf2f(u0.z), acc.z);
    acc.w = fmaf(w0, bf2f(u0.w), acc.w);
  }
  const float inv = 1.f / fmaxf(denom, 1e-6f);
  acc.x *= inv; acc.y *= inv; acc.z *= inv; acc.w *= inv;
  *(float4*)(out + (size_t)d * IN_CH + lane * 4) = acc;
}

// ---------------------------------------------------------------------------
extern "C" void kernel_launch(void* const* d_in, const int* in_sizes, int n_in,
                              void* d_out, int out_size, void* d_ws,
                              size_t ws_size, hipStream_t stream) {
  const float* x      = (const float*)d_in[0];
  const int*   ei     = (const int*)d_in[1];   // [2, E]: row0=src, row1=dst
  const float* W      = (const float*)d_in[2];
  const float* attn_l = (const float*)d_in[3];
  const float* attn_r = (const float*)d_in[4];
  float* out = (float*)d_out;

  const int n = in_sizes[0] / IN_CH;   // 50000
  const int E = in_sizes[1] / 2;       // 800000
  const int Etot = E + n;

  short* xpb   = (short*)d_ws;                     // n*256 bf16
  short* Wb    = xpb + (size_t)n * IN_CH;          // 65536 bf16
  float* al    = (float*)(Wb + IN_CH * IN_CH);     // n*8 f
  float* ar    = al + (size_t)n * HEADS;           // n*8 f
  int*   deg   = (int*)(ar + (size_t)n * HEADS);   // n i (zeroed)
  int*   cnt   = deg + n;                          // n i (zeroed)
  int*   cursor = cnt + n;                         // 1 i (zeroed)
  int*   off   = cursor + 1;                       // n i
  int*   csrs  = off + n;                          // Etot i

  hipMemsetAsync(deg, 0, ((size_t)2 * n + 1) * sizeof(int), stream);

  w_convert<<<(IN_CH * IN_CH + 255) / 256, 256, 0, stream>>>(W, Wb);

  gemm_mfma<<<(n + 31) / 32, 64, 0, stream>>>(x, Wb, xpb, n);

  node_attn<<<(n * HEADS + 255) / 256, 256, 0, stream>>>(xpb, attn_l, attn_r,
                                                         al, ar, n);

  csr_count<<<(Etot + 255) / 256, 256, 0, stream>>>(ei + E, deg, E, n);
  csr_alloc<<<(n + 255) / 256, 256, 0, stream>>>(deg, off, cursor, n);
  csr_fill<<<(Etot + 255) / 256, 256, 0, stream>>>(ei, ei + E, off, cnt, csrs,
                                                   E, n);

  const long long g_threads = (long long)n * 64;
  gat_gather<<<(int)((g_threads + 255) / 256), 256, 0, stream>>>(
      csrs, off, deg, xpb, al, ar, out, n);
}

// Round 5
// 307.565 us; speedup vs baseline: 10.9575x; 1.0237x over previous
//
#include <hip/hip_runtime.h>
#include <math.h>

#define IN_CH   256
#define HEADS   8
#define OUT_CH  32
// HEADS*OUT_CH == IN_CH == 256

typedef __attribute__((ext_vector_type(8))) short s16x8;   // 8 bf16 (4 VGPRs)
typedef __attribute__((ext_vector_type(4))) float f32x4;   // MFMA C/D

__device__ inline short f2bf(float f) {
  unsigned u = __builtin_bit_cast(unsigned, f);
  u += 0x7fffu + ((u >> 16) & 1u);           // RNE
  return (short)(u >> 16);
}
__device__ inline float bf2f(unsigned short u) {
  unsigned v = ((unsigned)u) << 16;
  return __builtin_bit_cast(float, v);
}

// ---------------------------------------------------------------------------
// Kernel 0: W fp32 -> bf16 (one-shot, 65536 elements).
// ---------------------------------------------------------------------------
__global__ __launch_bounds__(256) void w_convert(const float* __restrict__ W,
                                                 short* __restrict__ Wb) {
  const int i = blockIdx.x * blockDim.x + threadIdx.x;
  if (i < IN_CH * IN_CH) Wb[i] = f2bf(W[i]);
}

// ---------------------------------------------------------------------------
// Kernel 1 (fused): GEMM xp=bf16(x@W^T) + attn-dot epilogue, with csr_count
// running concurrently in trailing blocks (independent work, same dispatch).
//
// GEMM: one wave per block. Wave w covers M-tile 32 rows (2 MFMA subtiles)
// and an N-HALF (8 of 16 tiles) -> 2x the waves of the R4 version (3126 =
// ~3 waves/SIMD) for latency hiding at the same total W traffic.
// Epilogue: al[m,h] = sum_col xp[m][col]*attn_l[col] accumulated per head
// on the fp32 accumulators (2 tiles per head), reduced across the 16 mrow
// lanes via shfl_xor — node_attn kernel (25.6 MB re-read) deleted.
// A: lane holds x[m0+ms*16+(lane&15)][32*ks+(lane>>4)*8+j]
// D: col = lane&15, row = (lane>>4)*4 + reg   (m89-verified)
// ---------------------------------------------------------------------------
__global__ __launch_bounds__(64) void fused_gemm_count(
    const float* __restrict__ x, const short* __restrict__ Wb,
    const float* __restrict__ attn_l, const float* __restrict__ attn_r,
    short* __restrict__ xpb, float* __restrict__ al, float* __restrict__ ar,
    const int* __restrict__ dst_idx, int* __restrict__ deg,
    int E, int n, int gemm_blocks) {
  if ((int)blockIdx.x >= gemm_blocks) {
    // ---- csr_count part: in-degree histogram (self-loops e>=E -> e-E) ----
    const int nb = gridDim.x - gemm_blocks;
    const int Etot = E + n;
    const int stride = nb * 64;
    for (int e = ((int)blockIdx.x - gemm_blocks) * 64 + (int)threadIdx.x;
         e < Etot; e += stride) {
      const int d = (e < E) ? dst_idx[e] : (e - E);
      atomicAdd(&deg[d], 1);
    }
    return;
  }

  // ---- GEMM part ----
  const int lane = threadIdx.x;
  const int mrow = lane & 15;
  const int kq = lane >> 4;
  const int w = blockIdx.x;
  const int m0 = (w >> 1) * 32;
  const int nh = w & 1;             // N-half: tiles [nh*8, nh*8+8)

  s16x8 afrag[2][8];
#pragma unroll
  for (int ms = 0; ms < 2; ++ms) {
    int m = m0 + ms * 16 + mrow;
    if (m >= n) m = n - 1;          // clamp; stores guarded
    const float* xr = x + (size_t)m * IN_CH + kq * 8;
#pragma unroll
    for (int ks = 0; ks < 8; ++ks) {
      float4 lo = *(const float4*)(xr + ks * 32);
      float4 hi = *(const float4*)(xr + ks * 32 + 4);
      s16x8 a;
      a[0] = f2bf(lo.x); a[1] = f2bf(lo.y); a[2] = f2bf(lo.z); a[3] = f2bf(lo.w);
      a[4] = f2bf(hi.x); a[5] = f2bf(hi.y); a[6] = f2bf(hi.z); a[7] = f2bf(hi.w);
      afrag[ms][ks] = a;
    }
  }

  float accl[2][4] = {};   // per-head attn_l partials (current head)
  float accr[2][4] = {};

#pragma unroll
  for (int tt = 0; tt < 8; ++tt) {
    const int t = nh * 8 + tt;
    f32x4 acc0 = {0.f, 0.f, 0.f, 0.f};
    f32x4 acc1 = {0.f, 0.f, 0.f, 0.f};
    const short* wr = Wb + (size_t)(t * 16 + mrow) * IN_CH + kq * 8;
#pragma unroll
    for (int ks = 0; ks < 8; ++ks) {
      s16x8 b = *(const s16x8*)(wr + ks * 32);
      acc0 = __builtin_amdgcn_mfma_f32_16x16x32_bf16(afrag[0][ks], b, acc0, 0, 0, 0);
      acc1 = __builtin_amdgcn_mfma_f32_16x16x32_bf16(afrag[1][ks], b, acc1, 0, 0, 0);
    }
    const int col = t * 16 + mrow;
    const float la = attn_l[col];
    const float ra = attn_r[col];
#pragma unroll
    for (int r = 0; r < 4; ++r) {
      accl[0][r] += acc0[r] * la; accr[0][r] += acc0[r] * ra;
      accl[1][r] += acc1[r] * la; accr[1][r] += acc1[r] * ra;
      const int row0 = m0 + kq * 4 + r;
      if (row0 < n) xpb[(size_t)row0 * IN_CH + col] = f2bf(acc0[r]);
      const int row1 = m0 + 16 + kq * 4 + r;
      if (row1 < n) xpb[(size_t)row1 * IN_CH + col] = f2bf(acc1[r]);
    }
    if (tt & 1) {                    // 2 tiles (=1 head) accumulated: flush
      const int h = t >> 1;
#pragma unroll
      for (int ms = 0; ms < 2; ++ms)
#pragma unroll
        for (int r = 0; r < 4; ++r) {
          float vl = accl[ms][r], vr = accr[ms][r];
#pragma unroll
          for (int o = 1; o < 16; o <<= 1) {
            vl += __shfl_xor(vl, o);
            vr += __shfl_xor(vr, o);
          }
          if (mrow == 0) {
            const int row = m0 + ms * 16 + kq * 4 + r;
            if (row < n) {
              al[row * HEADS + h] = vl;
              ar[row * HEADS + h] = vr;
            }
          }
          accl[ms][r] = 0.f;
          accr[ms][r] = 0.f;
        }
    }
  }
}

// ---------------------------------------------------------------------------
// Kernel 2: bucket allocation without a global scan. Wave shuffle-scan of
// deg, one cursor atomicAdd per wave; bucket order is run-dependent (fine:
// consumer is a sum).
// ---------------------------------------------------------------------------
__global__ __launch_bounds__(256) void csr_alloc(
    const int* __restrict__ deg, int* __restrict__ off,
    int* __restrict__ cursor, int n) {
  const int d = blockIdx.x * blockDim.x + threadIdx.x;
  const int lane = threadIdx.x & 63;
  const int v = (d < n) ? deg[d] : 0;
  int incl = v;
#pragma unroll
  for (int o = 1; o < 64; o <<= 1) {
    int t = __shfl_up(incl, o);
    if (lane >= o) incl += t;
  }
  const int total = __shfl(incl, 63);
  int base = 0;
  if (lane == 63) base = atomicAdd(cursor, total);
  base = __shfl(base, 63);
  if (d < n) off[d] = base + incl - v;
}

// ---------------------------------------------------------------------------
// Kernel 3: bucket fill: csr_src[off[d] + pos] = s.
// ---------------------------------------------------------------------------
__global__ __launch_bounds__(256) void csr_fill(
    const int* __restrict__ src_idx, const int* __restrict__ dst_idx,
    const int* __restrict__ off, int* __restrict__ cnt,
    int* __restrict__ csr_src, int E, int n) {
  const int e = blockIdx.x * blockDim.x + threadIdx.x;
  if (e >= E + n) return;
  int s, d;
  if (e < E) {
    s = src_idx[e];
    d = dst_idx[e];
  } else {
    s = d = e - E;
  }
  const int p = atomicAdd(&cnt[d], 1);
  csr_src[off[d] + p] = s;
}

// ---------------------------------------------------------------------------
// Kernel 4: gather-aggregate, bf16 payload. One wave per dst node; lane l
// covers channels l*4..l*4+3 (head = l>>3). Softmax denominator + weighted
// numerator in one pass, fp32 accumulate, one coalesced store. No atomics.
// 4-edge unroll keeps 4 row-loads in flight. Max-subtraction cancels
// exactly; 1e-6 clamp can't trigger (self-loop).
// ---------------------------------------------------------------------------
__global__ __launch_bounds__(256) void gat_gather(
    const int* __restrict__ csr_src, const int* __restrict__ off,
    const int* __restrict__ deg, const short* __restrict__ xpb,
    const float* __restrict__ al, const float* __restrict__ ar,
    float* __restrict__ out, int n) {
  const int gid = blockIdx.x * blockDim.x + threadIdx.x;
  const int d = gid >> 6;
  const int lane = gid & 63;
  if (d >= n) return;
  const int h = lane >> 3;
  const int start = off[d];
  const int cnt = deg[d];
  const float ard = ar[d * HEADS + h];

  float4 acc = make_float4(0.f, 0.f, 0.f, 0.f);
  float denom = 0.f;
  int j = 0;
  for (; j + 4 <= cnt; j += 4) {
    int s[4];
    ushort4 u[4];
    float wgt[4];
#pragma unroll
    for (int i = 0; i < 4; ++i) s[i] = csr_src[start + j + i];
#pragma unroll
    for (int i = 0; i < 4; ++i)
      u[i] = *(const ushort4*)(xpb + (size_t)s[i] * IN_CH + lane * 4);
#pragma unroll
    for (int i = 0; i < 4; ++i) {
      float a = al[s[i] * HEADS + h] + ard;
      a = a > 0.f ? a : 0.2f * a;
      wgt[i] = __expf(a);
      denom += wgt[i];
    }
#pragma unroll
    for (int i = 0; i < 4; ++i) {
      acc.x = fmaf(wgt[i], bf2f(u[i].x), acc.x);
      acc.y = fmaf(wgt[i], bf2f(u[i].y), acc.y);
      acc.z = fmaf(wgt[i], bf2f(u[i].z), acc.z);
      acc.w = fmaf(wgt[i], bf2f(u[i].w), acc.w);
    }
  }
  for (; j < cnt; ++j) {
    const int s0 = csr_src[start + j];
    const ushort4 u0 = *(const ushort4*)(xpb + (size_t)s0 * IN_CH + lane * 4);
    float a0 = al[s0 * HEADS + h] + ard;
    a0 = a0 > 0.f ? a0 : 0.2f * a0;
    const float w0 = __expf(a0);
    denom += w0;
    acc.x = fmaf(w0, bf2f(u0.x), acc.x);
    acc.y = fmaf(w0, bf2f(u0.y), acc.y);
    acc.z = fmaf(w0, bf2f(u0.z), acc.z);
    acc.w = fmaf(w0, bf2f(u0.w), acc.w);
  }
  const float inv = 1.f / fmaxf(denom, 1e-6f);
  acc.x *= inv; acc.y *= inv; acc.z *= inv; acc.w *= inv;
  *(float4*)(out + (size_t)d * IN_CH + lane * 4) = acc;
}

// ---------------------------------------------------------------------------
extern "C" void kernel_launch(void* const* d_in, const int* in_sizes, int n_in,
                              void* d_out, int out_size, void* d_ws,
                              size_t ws_size, hipStream_t stream) {
  const float* x      = (const float*)d_in[0];
  const int*   ei     = (const int*)d_in[1];   // [2, E]: row0=src, row1=dst
  const float* W      = (const float*)d_in[2];
  const float* attn_l = (const float*)d_in[3];
  const float* attn_r = (const float*)d_in[4];
  float* out = (float*)d_out;

  const int n = in_sizes[0] / IN_CH;   // 50000
  const int E = in_sizes[1] / 2;       // 800000
  const int Etot = E + n;

  short* xpb    = (short*)d_ws;                     // n*256 bf16
  short* Wb     = xpb + (size_t)n * IN_CH;          // 65536 bf16
  float* al     = (float*)(Wb + IN_CH * IN_CH);     // n*8 f
  float* ar     = al + (size_t)n * HEADS;           // n*8 f
  int*   deg    = (int*)(ar + (size_t)n * HEADS);   // n i (zeroed)
  int*   cnt    = deg + n;                          // n i (zeroed)
  int*   cursor = cnt + n;                          // 1 i (zeroed)
  int*   off    = cursor + 1;                       // n i
  int*   csrs   = off + n;                          // Etot i

  hipMemsetAsync(deg, 0, ((size_t)2 * n + 1) * sizeof(int), stream);

  w_convert<<<(IN_CH * IN_CH + 255) / 256, 256, 0, stream>>>(W, Wb);

  const int gemm_blocks = 2 * ((n + 31) / 32);   // 3126 one-wave blocks
  const int count_blocks = 1024;
  fused_gemm_count<<<gemm_blocks + count_blocks, 64, 0, stream>>>(
      x, Wb, attn_l, attn_r, xpb, al, ar, ei + E, deg, E, n, gemm_blocks);

  csr_alloc<<<(n + 255) / 256, 256, 0, stream>>>(deg, off, cursor, n);
  csr_fill<<<(Etot + 255) / 256, 256, 0, stream>>>(ei, ei + E, off, cnt, csrs,
                                                   E, n);

  const long long g_threads = (long long)n * 64;
  gat_gather<<<(int)((g_threads + 255) / 256), 256, 0, stream>>>(
      csrs, off, deg, xpb, al, ar, out, n);
}